// Round 2
// baseline (349.976 us; speedup 1.0000x reference)
//
#include <hip/hip_runtime.h>
#include <math.h>

namespace {
constexpr int Bb = 32, Nn = 32, Ll = 512, Mm = 64, Ff = 64;
constexpr int TL = 32;          // L-tile
constexpr int NT = Ll / TL;     // 16
constexpr float EPSV = 1e-8f;
constexpr size_t AW_BYTES = (size_t)Nn * Ll * Mm * sizeof(float);  // 4 MB
}

// ---------------------------------------------------------------------------
// Kernel 1: alpha'[n][l][m] = alpha / (denom_m + eps), written to d_ws.
// Grid 32 (one block per n), 256 threads.
// ---------------------------------------------------------------------------
__global__ __launch_bounds__(256)
void alpha_kernel(const float* __restrict__ t_in,
                  const float* __restrict__ t_left,
                  const float* __restrict__ t_right,
                  const float* __restrict__ kappa,
                  float* __restrict__ aw)
{
    const int n  = blockIdx.x;
    const int m  = threadIdx.x & 63;
    const int lq = threadIdx.x >> 6;     // 0..3

    __shared__ float ts[Ll];
    __shared__ float dred[4][Mm];

    for (int i = threadIdx.x; i < Ll; i += 256) ts[i] = t_in[i];

    const float kap = kappa[n];
    const float kk  = fmaxf(kap, 0.0f) + log1pf(expf(-fabsf(kap))); // softplus
    const float ik  = 1.0f / kk;
    const float tlv = t_left [n * Mm + m];
    const float trv = t_right[n * Mm + m];
    __syncthreads();

    float* an = aw + (size_t)n * Ll * Mm;
    float dsum = 0.0f;
    for (int l = lq; l < Ll; l += 4) {
        const float tv = ts[l];
        const float a  = 1.0f / ((1.0f + __expf((tv - trv) * ik)) *
                                 (1.0f + __expf((tlv - tv) * ik)));
        an[l * Mm + m] = a;
        dsum += a;
    }
    dred[lq][m] = dsum;
    __syncthreads();
    const float d    = dred[0][m] + dred[1][m] + dred[2][m] + dred[3][m];
    const float invd = 1.0f / (d + EPSV);
    // scale own (l,m) elements (same thread wrote them -> same-lane RAW, ordered)
    for (int l = lq; l < Ll; l += 4) {
        an[l * Mm + m] *= invd;
    }
}

// ---------------------------------------------------------------------------
// Kernel 2: out[b,n,m,f] = sum_l alpha'[n,l,m] * x[b,n,l,f]
// One block per (b,n): grid 1024 -> 4 blocks/CU, 16 waves/CU.
// 256 threads, 4m x 4f register tile per thread.
// ---------------------------------------------------------------------------
__global__ __launch_bounds__(256)
void wagg_main(const float* __restrict__ x_aug,
               const float* __restrict__ aw,
               float* __restrict__ out)
{
    const int n = blockIdx.x & (Nn - 1);
    const int b = blockIdx.x >> 5;
    const int tid = threadIdx.x;

    __shared__ float xs[TL][Ff];   // 8 KB
    __shared__ float as_[TL][Mm];  // 8 KB

    const int tf = tid & 15;       // f block: 16 x 4f = 64
    const int tm = tid >> 4;       // m block: 16 x 4m = 64

    const float* xbase = x_aug + (size_t)(b * Nn + n) * (Ll * Ff);
    const float* abase = aw    + (size_t)n * Ll * Mm;

    float acc[4][4];
    #pragma unroll
    for (int i = 0; i < 4; ++i)
        #pragma unroll
        for (int j = 0; j < 4; ++j) acc[i][j] = 0.0f;

    float4 xst[2], ast[2];

    // ---- prologue: stage tile 0 ----
    {
        const float4* xsrc = (const float4*)xbase;
        const float4* asrc = (const float4*)abase;
        xst[0] = xsrc[tid]; xst[1] = xsrc[256 + tid];
        ast[0] = asrc[tid]; ast[1] = asrc[256 + tid];
        ((float4*)xs)[tid]        = xst[0];
        ((float4*)xs)[256 + tid]  = xst[1];
        ((float4*)as_)[tid]       = ast[0];
        ((float4*)as_)[256 + tid] = ast[1];
    }
    __syncthreads();

    for (int tile = 0; tile < NT; ++tile) {
        // register-prefetch next tile (overlaps with FMA below)
        if (tile + 1 < NT) {
            const float4* xsrc = (const float4*)(xbase + (size_t)(tile + 1) * TL * Ff);
            const float4* asrc = (const float4*)(abase + (size_t)(tile + 1) * TL * Mm);
            xst[0] = xsrc[tid]; xst[1] = xsrc[256 + tid];
            ast[0] = asrc[tid]; ast[1] = asrc[256 + tid];
        }
        #pragma unroll
        for (int lt = 0; lt < TL; ++lt) {
            const float4 av = *(const float4*)&as_[lt][tm * 4];
            const float4 xv = *(const float4*)&xs[lt][tf * 4];
            const float a0 = av.x, a1 = av.y, a2 = av.z, a3 = av.w;
            const float x0 = xv.x, x1 = xv.y, x2 = xv.z, x3 = xv.w;
            acc[0][0] = fmaf(a0, x0, acc[0][0]);
            acc[0][1] = fmaf(a0, x1, acc[0][1]);
            acc[0][2] = fmaf(a0, x2, acc[0][2]);
            acc[0][3] = fmaf(a0, x3, acc[0][3]);
            acc[1][0] = fmaf(a1, x0, acc[1][0]);
            acc[1][1] = fmaf(a1, x1, acc[1][1]);
            acc[1][2] = fmaf(a1, x2, acc[1][2]);
            acc[1][3] = fmaf(a1, x3, acc[1][3]);
            acc[2][0] = fmaf(a2, x0, acc[2][0]);
            acc[2][1] = fmaf(a2, x1, acc[2][1]);
            acc[2][2] = fmaf(a2, x2, acc[2][2]);
            acc[2][3] = fmaf(a2, x3, acc[2][3]);
            acc[3][0] = fmaf(a3, x0, acc[3][0]);
            acc[3][1] = fmaf(a3, x1, acc[3][1]);
            acc[3][2] = fmaf(a3, x2, acc[3][2]);
            acc[3][3] = fmaf(a3, x3, acc[3][3]);
        }
        __syncthreads();
        if (tile + 1 < NT) {
            ((float4*)xs)[tid]        = xst[0];
            ((float4*)xs)[256 + tid]  = xst[1];
            ((float4*)as_)[tid]       = ast[0];
            ((float4*)as_)[256 + tid] = ast[1];
        }
        __syncthreads();
    }

    // ---- epilogue: alpha' already carries 1/(denom+eps) -> pure store ----
    float* obase = out + (size_t)(b * Nn + n) * Mm * Ff;
    #pragma unroll
    for (int i = 0; i < 4; ++i) {
        float4 o;
        o.x = acc[i][0]; o.y = acc[i][1]; o.z = acc[i][2]; o.w = acc[i][3];
        *(float4*)&obase[(tm * 4 + i) * Ff + tf * 4] = o;
    }
}

// ---------------------------------------------------------------------------
// Fallback (ws too small): Round-1 kernel, known-correct. grid 256, BG=4.
// ---------------------------------------------------------------------------
__global__ __launch_bounds__(256, 1)
void wagg_fallback(const float* __restrict__ x_aug,
                   const float* __restrict__ t_in,
                   const float* __restrict__ t_left,
                   const float* __restrict__ t_right,
                   const float* __restrict__ kappa,
                   float* __restrict__ out)
{
    constexpr int BG = 4;
    const int n   = blockIdx.x >> 3;
    const int b0  = (blockIdx.x & 7) * BG;
    const int tid = threadIdx.x;

    __shared__ float xs[BG][TL][Ff];
    __shared__ float as_[TL][Mm];
    __shared__ float ts[Ll];
    __shared__ float dred[4][Mm];

    for (int i = tid; i < Ll; i += 256) ts[i] = t_in[i];

    const int am  = tid & 63;
    const int alq = tid >> 6;
    const float kap = kappa[n];
    const float kk  = fmaxf(kap, 0.0f) + log1pf(expf(-fabsf(kap)));
    const float ik  = 1.0f / kk;
    const float tlv = t_left [n * Mm + am];
    const float trv = t_right[n * Mm + am];

    const int bs   = tid >> 6;
    const int lane = tid & 63;
    const int mi   = (lane >> 3) << 3;
    const int fi   = (lane & 7) << 3;

    float acc[8][8];
    #pragma unroll
    for (int i = 0; i < 8; ++i)
        #pragma unroll
        for (int j = 0; j < 8; ++j) acc[i][j] = 0.0f;

    float4 stg[8];
    float  aval[8];
    float  dpart = 0.0f;

    __syncthreads();
    {
        #pragma unroll
        for (int k = 0; k < 8; ++k) {
            const int g = k * 256 + tid;
            const int gbs = g >> 9, r = (g >> 4) & 31, fq = (g & 15) << 2;
            stg[k] = *(const float4*)(x_aug
                + (size_t)((b0 + gbs) * Nn + n) * (Ll * Ff) + (size_t)r * Ff + fq);
        }
        #pragma unroll
        for (int i = 0; i < 8; ++i) {
            const float tv = ts[alq + (i << 2)];
            const float a = 1.0f / ((1.0f + __expf((tv - trv) * ik)) *
                                    (1.0f + __expf((tlv - tv) * ik)));
            aval[i] = a; dpart += a;
        }
        #pragma unroll
        for (int k = 0; k < 8; ++k) ((float4*)xs)[k * 256 + tid] = stg[k];
        #pragma unroll
        for (int i = 0; i < 8; ++i) as_[alq + (i << 2)][am] = aval[i];
    }
    __syncthreads();

    for (int tile = 0; tile < NT; ++tile) {
        if (tile + 1 < NT) {
            const int l0 = (tile + 1) * TL;
            #pragma unroll
            for (int k = 0; k < 8; ++k) {
                const int g = k * 256 + tid;
                const int gbs = g >> 9, r = (g >> 4) & 31, fq = (g & 15) << 2;
                stg[k] = *(const float4*)(x_aug
                    + (size_t)((b0 + gbs) * Nn + n) * (Ll * Ff)
                    + (size_t)(l0 + r) * Ff + fq);
            }
            #pragma unroll
            for (int i = 0; i < 8; ++i) {
                const float tv = ts[l0 + alq + (i << 2)];
                const float a = 1.0f / ((1.0f + __expf((tv - trv) * ik)) *
                                        (1.0f + __expf((tlv - tv) * ik)));
                aval[i] = a; dpart += a;
            }
        }
        #pragma unroll 4
        for (int lt = 0; lt < TL; ++lt) {
            float av[8], xv[8];
            *(float4*)&av[0] = *(const float4*)&as_[lt][mi];
            *(float4*)&av[4] = *(const float4*)&as_[lt][mi + 4];
            *(float4*)&xv[0] = *(const float4*)&xs[bs][lt][fi];
            *(float4*)&xv[4] = *(const float4*)&xs[bs][lt][fi + 4];
            #pragma unroll
            for (int i = 0; i < 8; ++i)
                #pragma unroll
                for (int j = 0; j < 8; ++j)
                    acc[i][j] = fmaf(av[i], xv[j], acc[i][j]);
        }
        __syncthreads();
        if (tile + 1 < NT) {
            #pragma unroll
            for (int k = 0; k < 8; ++k) ((float4*)xs)[k * 256 + tid] = stg[k];
            #pragma unroll
            for (int i = 0; i < 8; ++i) as_[alq + (i << 2)][am] = aval[i];
        }
        __syncthreads();
    }

    dred[alq][am] = dpart;
    __syncthreads();
    if (tid < Mm) {
        const float d = dred[0][tid] + dred[1][tid] + dred[2][tid] + dred[3][tid];
        dred[0][tid] = 1.0f / (d + EPSV);
    }
    __syncthreads();

    const size_t obase = ((size_t)(b0 + bs) * Nn + n) * Mm;
    #pragma unroll
    for (int i = 0; i < 8; ++i) {
        const float inv = dred[0][mi + i];
        float o[8];
        #pragma unroll
        for (int j = 0; j < 8; ++j) o[j] = acc[i][j] * inv;
        float* dst = out + (obase + (mi + i)) * Ff + fi;
        *(float4*)dst       = *(float4*)&o[0];
        *((float4*)dst + 1) = *(float4*)&o[4];
    }
}

extern "C" void kernel_launch(void* const* d_in, const int* in_sizes, int n_in,
                              void* d_out, int out_size, void* d_ws, size_t ws_size,
                              hipStream_t stream)
{
    const float* x_aug   = (const float*)d_in[0];
    const float* t_in    = (const float*)d_in[1];
    const float* t_left  = (const float*)d_in[2];
    const float* t_right = (const float*)d_in[3];
    const float* kappa   = (const float*)d_in[4];
    float* out = (float*)d_out;

    if (ws_size >= AW_BYTES) {
        float* aw = (float*)d_ws;
        hipLaunchKernelGGL(alpha_kernel, dim3(Nn), dim3(256), 0, stream,
                           t_in, t_left, t_right, kappa, aw);
        hipLaunchKernelGGL(wagg_main, dim3(Bb * Nn), dim3(256), 0, stream,
                           x_aug, aw, out);
    } else {
        hipLaunchKernelGGL(wagg_fallback, dim3(Nn * 8), dim3(256), 0, stream,
                           x_aug, t_in, t_left, t_right, kappa, out);
    }
}

// Round 3
// 236.272 us; speedup vs baseline: 1.4812x; 1.4812x over previous
//
#include <hip/hip_runtime.h>
#include <math.h>

typedef unsigned short u16;
typedef unsigned int   u32;
typedef __attribute__((ext_vector_type(8))) short short8;
typedef __attribute__((ext_vector_type(4))) float f32x4;

namespace {
constexpr int Bb = 32, Nn = 32, Ll = 512, Mm = 64, Ff = 64;
constexpr int TL  = 32;           // K-tile in l (= one MFMA K step)
constexpr int NT  = Ll / TL;      // 16
constexpr int TLP = 40;           // padded row length (ushorts): 80B stride, conflict-free b128
constexpr float EPSV = 1e-8f;
constexpr size_t AW_ELEMS = (size_t)Nn * Ll * Mm;          // 1M ushorts per array
constexpr size_t AW_BYTES = AW_ELEMS * 2 * 2;              // awh + awl = 4 MB
}

__device__ __forceinline__ u16 bf16rne(float x) {
    u32 u = __float_as_uint(x);
    return (u16)((u + 0x7fffu + ((u >> 16) & 1u)) >> 16);
}
__device__ __forceinline__ float bf16tof(u16 h) {
    return __uint_as_float(((u32)h) << 16);
}

// ---------------------------------------------------------------------------
// Kernel A: alpha'[n][l][m] = alpha/(denom_m+eps), split into bf16 hi/lo,
// stored TILED: aw?[ ((n*16 + l/32)*64 + m)*32 + l%32 ].  Grid 32, 256 thr.
// ---------------------------------------------------------------------------
__global__ __launch_bounds__(256)
void alpha_kernel(const float* __restrict__ t_in,
                  const float* __restrict__ t_left,
                  const float* __restrict__ t_right,
                  const float* __restrict__ kappa,
                  u16* __restrict__ awh, u16* __restrict__ awl)
{
    const int n   = blockIdx.x;
    const int tid = threadIdx.x;

    __shared__ float ts[Ll];
    __shared__ float dred[4][Mm];
    __shared__ float inv[Mm];

    for (int i = tid; i < Ll; i += 256) ts[i] = t_in[i];

    const float kap = kappa[n];
    const float kk  = fmaxf(kap, 0.0f) + log1pf(expf(-fabsf(kap))); // softplus
    const float ik  = 1.0f / kk;

    // phase 1: denominators
    const int m1 = tid & 63, lq = tid >> 6;
    const float tl1 = t_left[n * Mm + m1], tr1 = t_right[n * Mm + m1];
    __syncthreads();
    float ds = 0.0f;
    for (int l = lq; l < Ll; l += 4) {
        const float tv = ts[l];
        ds += 1.0f / ((1.0f + __expf((tv - tr1) * ik)) *
                      (1.0f + __expf((tl1 - tv) * ik)));
    }
    dred[lq][m1] = ds;
    __syncthreads();
    if (tid < Mm)
        inv[tid] = 1.0f / (dred[0][tid] + dred[1][tid] + dred[2][tid] + dred[3][tid] + EPSV);
    __syncthreads();

    // phase 2: recompute, prescale, split, store tiled
    const int mm = tid >> 2, seg = tid & 3;
    const float tl2 = t_left[n * Mm + mm], tr2 = t_right[n * Mm + mm];
    const float iv = inv[mm];
    for (int l = seg * 128; l < seg * 128 + 128; l += 2) {
        float tv = ts[l];
        const float v0 = iv / ((1.0f + __expf((tv - tr2) * ik)) *
                               (1.0f + __expf((tl2 - tv) * ik)));
        tv = ts[l + 1];
        const float v1 = iv / ((1.0f + __expf((tv - tr2) * ik)) *
                               (1.0f + __expf((tl2 - tv) * ik)));
        const u16 h0 = bf16rne(v0), h1 = bf16rne(v1);
        const u16 s0 = bf16rne(v0 - bf16tof(h0)), s1 = bf16rne(v1 - bf16tof(h1));
        const size_t idx = ((size_t)(n * NT + (l >> 5)) * Mm + mm) * TL + (l & 31);
        *(u32*)&awh[idx] = (u32)h0 | ((u32)h1 << 16);
        *(u32*)&awl[idx] = (u32)s0 | ((u32)s1 << 16);
    }
}

// ---------------------------------------------------------------------------
// Kernel B: MFMA main.  Block = (b-pair, n), grid 512, 256 thr (4 waves).
// Wave w: b = b0 + (w&1), m-half = (w>>1).  3-pass split-precision bf16 MFMA.
// ---------------------------------------------------------------------------
__global__ __launch_bounds__(256, 2)
void wagg_mfma(const float* __restrict__ x_aug,
               const u16* __restrict__ awh, const u16* __restrict__ awl,
               float* __restrict__ out)
{
    const int n   = blockIdx.x & 31;
    const int b0  = (blockIdx.x >> 5) * 2;
    const int tid = threadIdx.x;

    __shared__ u16 ah_s[2][Mm * TLP];        // alpha-hi   [m][l]  5 KB/stage
    __shared__ u16 al_s[2][Mm * TLP];        // alpha-lo
    __shared__ u16 xh_s[2][2 * Ff * TLP];    // x-hi  [b][f][l]   10 KB/stage
    __shared__ u16 xl_s[2][2 * Ff * TLP];    // x-lo              total 60 KB

    // staging ids
    const int fq = tid & 15;                 // f quad (f = 4*fq + j)
    const int lp = tid >> 4;                 // 0..15, l = 2*lp
    const int am = tid & 63;                 // alpha row m
    const int aq = tid >> 6;                 // alpha 16B chunk 0..3

    const float* xb[2] = {
        x_aug + (size_t)(b0 * Nn + n) * (Ll * Ff),
        x_aug + (size_t)((b0 + 1) * Nn + n) * (Ll * Ff)
    };
    const u16* ahg = awh + (size_t)n * NT * Mm * TL;
    const u16* alg = awl + (size_t)n * NT * Mm * TL;

    // compute ids
    const int lane = tid & 63;
    const int w    = tid >> 6;
    const int bw   = w & 1;                  // which b this wave computes
    const int mg   = w >> 1;                 // which m-half (0: m<32, 1: m>=32)
    const int q    = lane >> 4;              // k-chunk / D-row-quad
    const int c    = lane & 15;              // A-row m / D-col f

    f32x4 acc[2][4];
    #pragma unroll
    for (int mi = 0; mi < 2; ++mi)
        #pragma unroll
        for (int ft = 0; ft < 4; ++ft)
            acc[mi][ft] = (f32x4){0.f, 0.f, 0.f, 0.f};

    float X[2][2][4];                        // [b][l/l+1][j]
    uint4 AH, AL;

    // ---- prologue: load + convert + write tile 0 into buf 0 ----
    {
        #pragma unroll
        for (int bi = 0; bi < 2; ++bi) {
            const float* p = xb[bi] + (size_t)(2 * lp) * Ff + fq * 4;
            *(float4*)X[bi][0] = *(const float4*)p;
            *(float4*)X[bi][1] = *(const float4*)(p + Ff);
        }
        AH = *(const uint4*)(ahg + (size_t)am * TL + aq * 8);
        AL = *(const uint4*)(alg + (size_t)am * TL + aq * 8);

        #pragma unroll
        for (int bi = 0; bi < 2; ++bi)
            #pragma unroll
            for (int j = 0; j < 4; ++j) {
                const float v0 = X[bi][0][j], v1 = X[bi][1][j];
                const u16 h0 = bf16rne(v0), h1 = bf16rne(v1);
                const u16 s0 = bf16rne(v0 - bf16tof(h0)), s1 = bf16rne(v1 - bf16tof(h1));
                const u32 off = (u32)(bi * Ff + fq * 4 + j) * TLP + 2 * lp;
                *(u32*)&xh_s[0][off] = (u32)h0 | ((u32)h1 << 16);
                *(u32*)&xl_s[0][off] = (u32)s0 | ((u32)s1 << 16);
            }
        *(uint4*)&ah_s[0][am * TLP + aq * 8] = AH;
        *(uint4*)&al_s[0][am * TLP + aq * 8] = AL;
    }
    __syncthreads();

    for (int tile = 0; tile < NT; ++tile) {
        const int cur = tile & 1, nxt = cur ^ 1;

        // prefetch tile+1 (global -> regs); consumed after MFMA section
        if (tile + 1 < NT) {
            const int l0 = (tile + 1) * TL;
            #pragma unroll
            for (int bi = 0; bi < 2; ++bi) {
                const float* p = xb[bi] + (size_t)(l0 + 2 * lp) * Ff + fq * 4;
                *(float4*)X[bi][0] = *(const float4*)p;
                *(float4*)X[bi][1] = *(const float4*)(p + Ff);
            }
            const size_t ao = (size_t)(tile + 1) * Mm * TL + am * TL + aq * 8;
            AH = *(const uint4*)(ahg + ao);
            AL = *(const uint4*)(alg + ao);
        }

        // fragment reads + 24 MFMA on current buffer
        short8 ahf[2], alf[2], xhf[4], xlf[4];
        #pragma unroll
        for (int mi = 0; mi < 2; ++mi) {
            const u32 off = (u32)((mg * 2 + mi) * 16 + c) * TLP + q * 8;
            ahf[mi] = *(const short8*)&ah_s[cur][off];
            alf[mi] = *(const short8*)&al_s[cur][off];
        }
        #pragma unroll
        for (int ft = 0; ft < 4; ++ft) {
            const u32 off = (u32)(bw * Ff + ft * 16 + c) * TLP + q * 8;
            xhf[ft] = *(const short8*)&xh_s[cur][off];
            xlf[ft] = *(const short8*)&xl_s[cur][off];
        }
        #pragma unroll
        for (int mi = 0; mi < 2; ++mi)
            #pragma unroll
            for (int ft = 0; ft < 4; ++ft) {
                acc[mi][ft] = __builtin_amdgcn_mfma_f32_16x16x32_bf16(
                    ahf[mi], xhf[ft], acc[mi][ft], 0, 0, 0);
                acc[mi][ft] = __builtin_amdgcn_mfma_f32_16x16x32_bf16(
                    ahf[mi], xlf[ft], acc[mi][ft], 0, 0, 0);
                acc[mi][ft] = __builtin_amdgcn_mfma_f32_16x16x32_bf16(
                    alf[mi], xhf[ft], acc[mi][ft], 0, 0, 0);
            }

        // convert + write staged tile+1 into the other buffer
        if (tile + 1 < NT) {
            #pragma unroll
            for (int bi = 0; bi < 2; ++bi)
                #pragma unroll
                for (int j = 0; j < 4; ++j) {
                    const float v0 = X[bi][0][j], v1 = X[bi][1][j];
                    const u16 h0 = bf16rne(v0), h1 = bf16rne(v1);
                    const u16 s0 = bf16rne(v0 - bf16tof(h0)), s1 = bf16rne(v1 - bf16tof(h1));
                    const u32 off = (u32)(bi * Ff + fq * 4 + j) * TLP + 2 * lp;
                    *(u32*)&xh_s[nxt][off] = (u32)h0 | ((u32)h1 << 16);
                    *(u32*)&xl_s[nxt][off] = (u32)s0 | ((u32)s1 << 16);
                }
            *(uint4*)&ah_s[nxt][am * TLP + aq * 8] = AH;
            *(uint4*)&al_s[nxt][am * TLP + aq * 8] = AL;
        }
        __syncthreads();
    }

    // ---- epilogue: D[row=q*4+r][col=c] -> out[b][n][m][f] ----
    float* ob = out + (size_t)((b0 + bw) * Nn + n) * (Mm * Ff);
    #pragma unroll
    for (int mi = 0; mi < 2; ++mi) {
        const int mbase = (mg * 2 + mi) * 16 + q * 4;
        #pragma unroll
        for (int r = 0; r < 4; ++r)
            #pragma unroll
            for (int ft = 0; ft < 4; ++ft)
                ob[(size_t)(mbase + r) * Ff + ft * 16 + c] = acc[mi][ft][r];
    }
}

// ---------------------------------------------------------------------------
// Fallback (ws too small): Round-1 monolithic kernel, known-correct.
// ---------------------------------------------------------------------------
__global__ __launch_bounds__(256, 1)
void wagg_fallback(const float* __restrict__ x_aug,
                   const float* __restrict__ t_in,
                   const float* __restrict__ t_left,
                   const float* __restrict__ t_right,
                   const float* __restrict__ kappa,
                   float* __restrict__ out)
{
    constexpr int BG = 4;
    const int n   = blockIdx.x >> 3;
    const int b0  = (blockIdx.x & 7) * BG;
    const int tid = threadIdx.x;

    __shared__ float xs[BG][TL][Ff];
    __shared__ float as_[TL][Mm];
    __shared__ float ts[Ll];
    __shared__ float dred[4][Mm];

    for (int i = tid; i < Ll; i += 256) ts[i] = t_in[i];

    const int am  = tid & 63;
    const int alq = tid >> 6;
    const float kap = kappa[n];
    const float kk  = fmaxf(kap, 0.0f) + log1pf(expf(-fabsf(kap)));
    const float ik  = 1.0f / kk;
    const float tlv = t_left [n * Mm + am];
    const float trv = t_right[n * Mm + am];

    const int bs   = tid >> 6;
    const int lane = tid & 63;
    const int mi   = (lane >> 3) << 3;
    const int fi   = (lane & 7) << 3;

    float acc[8][8];
    #pragma unroll
    for (int i = 0; i < 8; ++i)
        #pragma unroll
        for (int j = 0; j < 8; ++j) acc[i][j] = 0.0f;

    float4 stg[8];
    float  aval[8];
    float  dpart = 0.0f;

    __syncthreads();
    {
        #pragma unroll
        for (int k = 0; k < 8; ++k) {
            const int g = k * 256 + tid;
            const int gbs = g >> 9, r = (g >> 4) & 31, fqq = (g & 15) << 2;
            stg[k] = *(const float4*)(x_aug
                + (size_t)((b0 + gbs) * Nn + n) * (Ll * Ff) + (size_t)r * Ff + fqq);
        }
        #pragma unroll
        for (int i = 0; i < 8; ++i) {
            const float tv = ts[alq + (i << 2)];
            const float a = 1.0f / ((1.0f + __expf((tv - trv) * ik)) *
                                    (1.0f + __expf((tlv - tv) * ik)));
            aval[i] = a; dpart += a;
        }
        #pragma unroll
        for (int k = 0; k < 8; ++k) ((float4*)xs)[k * 256 + tid] = stg[k];
        #pragma unroll
        for (int i = 0; i < 8; ++i) as_[alq + (i << 2)][am] = aval[i];
    }
    __syncthreads();

    for (int tile = 0; tile < NT; ++tile) {
        if (tile + 1 < NT) {
            const int l0 = (tile + 1) * TL;
            #pragma unroll
            for (int k = 0; k < 8; ++k) {
                const int g = k * 256 + tid;
                const int gbs = g >> 9, r = (g >> 4) & 31, fqq = (g & 15) << 2;
                stg[k] = *(const float4*)(x_aug
                    + (size_t)((b0 + gbs) * Nn + n) * (Ll * Ff)
                    + (size_t)(l0 + r) * Ff + fqq);
            }
            #pragma unroll
            for (int i = 0; i < 8; ++i) {
                const float tv = ts[l0 + alq + (i << 2)];
                const float a = 1.0f / ((1.0f + __expf((tv - trv) * ik)) *
                                        (1.0f + __expf((tlv - tv) * ik)));
                aval[i] = a; dpart += a;
            }
        }
        #pragma unroll 4
        for (int lt = 0; lt < TL; ++lt) {
            float av[8], xv[8];
            *(float4*)&av[0] = *(const float4*)&as_[lt][mi];
            *(float4*)&av[4] = *(const float4*)&as_[lt][mi + 4];
            *(float4*)&xv[0] = *(const float4*)&xs[bs][lt][fi];
            *(float4*)&xv[4] = *(const float4*)&xs[bs][lt][fi + 4];
            #pragma unroll
            for (int i = 0; i < 8; ++i)
                #pragma unroll
                for (int j = 0; j < 8; ++j)
                    acc[i][j] = fmaf(av[i], xv[j], acc[i][j]);
        }
        __syncthreads();
        if (tile + 1 < NT) {
            #pragma unroll
            for (int k = 0; k < 8; ++k) ((float4*)xs)[k * 256 + tid] = stg[k];
            #pragma unroll
            for (int i = 0; i < 8; ++i) as_[alq + (i << 2)][am] = aval[i];
        }
        __syncthreads();
    }

    dred[alq][am] = dpart;
    __syncthreads();
    if (tid < Mm) {
        const float d = dred[0][tid] + dred[1][tid] + dred[2][tid] + dred[3][tid];
        dred[0][tid] = 1.0f / (d + EPSV);
    }
    __syncthreads();

    const size_t obase = ((size_t)(b0 + bs) * Nn + n) * Mm;
    #pragma unroll
    for (int i = 0; i < 8; ++i) {
        const float inv = dred[0][mi + i];
        float o[8];
        #pragma unroll
        for (int j = 0; j < 8; ++j) o[j] = acc[i][j] * inv;
        float* dst = out + (obase + (mi + i)) * Ff + fi;
        *(float4*)dst       = *(float4*)&o[0];
        *((float4*)dst + 1) = *(float4*)&o[4];
    }
}

extern "C" void kernel_launch(void* const* d_in, const int* in_sizes, int n_in,
                              void* d_out, int out_size, void* d_ws, size_t ws_size,
                              hipStream_t stream)
{
    const float* x_aug   = (const float*)d_in[0];
    const float* t_in    = (const float*)d_in[1];
    const float* t_left  = (const float*)d_in[2];
    const float* t_right = (const float*)d_in[3];
    const float* kappa   = (const float*)d_in[4];
    float* out = (float*)d_out;

    if (ws_size >= AW_BYTES) {
        u16* awh = (u16*)d_ws;
        u16* awl = awh + AW_ELEMS;
        hipLaunchKernelGGL(alpha_kernel, dim3(Nn), dim3(256), 0, stream,
                           t_in, t_left, t_right, kappa, awh, awl);
        hipLaunchKernelGGL(wagg_mfma, dim3((Bb / 2) * Nn), dim3(256), 0, stream,
                           x_aug, awh, awl, out);
    } else {
        hipLaunchKernelGGL(wagg_fallback, dim3(Nn * 8), dim3(256), 0, stream,
                           x_aug, t_in, t_left, t_right, kappa, out);
    }
}

// Round 4
// 218.458 us; speedup vs baseline: 1.6020x; 1.0815x over previous
//
#include <hip/hip_runtime.h>
#include <math.h>

typedef unsigned short u16;
typedef unsigned int   u32;
typedef __attribute__((ext_vector_type(8))) short short8;
typedef __attribute__((ext_vector_type(4))) float f32x4;

namespace {
constexpr int Bb = 32, Nn = 32, Ll = 512, Mm = 64, Ff = 64;
constexpr int TL  = 32;           // K-tile in l (= one MFMA K step)
constexpr int NT  = Ll / TL;      // 16
constexpr int TLP = 40;           // padded row length (ushorts): 80B stride, conflict-free b128
constexpr float EPSV = 1e-8f;
constexpr size_t DEN_ELEMS = (size_t)Nn * Mm;              // 2048 f32 = 8 KB
constexpr size_t AW_ELEMS  = (size_t)Nn * Ll * Mm;         // 1M u16 per array
constexpr size_t WS_BYTES  = DEN_ELEMS * 4 + AW_ELEMS * 2 * 2;  // 8KB + 4MB
}

__device__ __forceinline__ u16 bf16rne(float x) {
    u32 u = __float_as_uint(x);
    return (u16)((u + 0x7fffu + ((u >> 16) & 1u)) >> 16);
}
__device__ __forceinline__ float bf16tof(u16 h) {
    return __uint_as_float(((u32)h) << 16);
}

// ---------------------------------------------------------------------------
// Kernel A1: denom[n][m] = sum_l alpha[n,l,m].  Grid 256 (n x 8 m-groups).
// ---------------------------------------------------------------------------
__global__ __launch_bounds__(256)
void denom_kernel(const float* __restrict__ t_in,
                  const float* __restrict__ t_left,
                  const float* __restrict__ t_right,
                  const float* __restrict__ kappa,
                  float* __restrict__ denom)
{
    const int n  = blockIdx.x >> 3;
    const int mg = blockIdx.x & 7;          // m group of 8
    const int tid = threadIdx.x;
    const int m8 = tid & 7;                 // 0..7
    const int lq = tid >> 3;                // 0..31

    __shared__ float ts[Ll];
    __shared__ float red[32][8];

    for (int i = tid; i < Ll; i += 256) ts[i] = t_in[i];

    const int m = mg * 8 + m8;
    const float kap = kappa[n];
    const float kk  = fmaxf(kap, 0.0f) + log1pf(expf(-fabsf(kap))); // softplus
    const float ik  = 1.0f / kk;
    const float tlv = t_left [n * Mm + m];
    const float trv = t_right[n * Mm + m];
    __syncthreads();

    float s = 0.0f;
    #pragma unroll
    for (int i = 0; i < 16; ++i) {
        const float tv = ts[lq + i * 32];
        s += 1.0f / ((1.0f + __expf((tv - trv) * ik)) *
                     (1.0f + __expf((tlv - tv) * ik)));
    }
    red[lq][m8] = s;
    __syncthreads();
    if (tid < 8) {
        float d = 0.0f;
        #pragma unroll
        for (int i = 0; i < 32; ++i) d += red[i][tid];
        denom[n * Mm + mg * 8 + tid] = d;
    }
}

// ---------------------------------------------------------------------------
// Kernel A2: alpha'[n,l,m] = alpha/(denom+eps), bf16 hi/lo split, stored
// tiled: aw?[ ((n*16 + l/32)*64 + m)*32 + l%32 ].  Grid 256 (n x 8 l-slices).
// ---------------------------------------------------------------------------
__global__ __launch_bounds__(256)
void alpha_kernel(const float* __restrict__ t_in,
                  const float* __restrict__ t_left,
                  const float* __restrict__ t_right,
                  const float* __restrict__ kappa,
                  const float* __restrict__ denom,
                  u16* __restrict__ awh, u16* __restrict__ awl)
{
    const int n  = blockIdx.x >> 3;
    const int ls = blockIdx.x & 7;          // l slice of 64
    const int tid = threadIdx.x;
    const int m  = tid & 63;
    const int li = tid >> 6;                // 0..3, 16 consecutive l's each

    __shared__ float ts2[64];
    if (tid < 64) ts2[tid] = t_in[ls * 64 + tid];

    const float kap = kappa[n];
    const float kk  = fmaxf(kap, 0.0f) + log1pf(expf(-fabsf(kap)));
    const float ik  = 1.0f / kk;
    const float tlv = t_left [n * Mm + m];
    const float trv = t_right[n * Mm + m];
    const float iv  = 1.0f / (denom[n * Mm + m] + EPSV);
    __syncthreads();

    #pragma unroll
    for (int j = 0; j < 16; j += 2) {
        const int ll = li * 16 + j;         // 0..63, even
        const int l  = ls * 64 + ll;
        float tv = ts2[ll];
        const float v0 = iv / ((1.0f + __expf((tv - trv) * ik)) *
                               (1.0f + __expf((tlv - tv) * ik)));
        tv = ts2[ll + 1];
        const float v1 = iv / ((1.0f + __expf((tv - trv) * ik)) *
                               (1.0f + __expf((tlv - tv) * ik)));
        const u16 h0 = bf16rne(v0), h1 = bf16rne(v1);
        const u16 s0 = bf16rne(v0 - bf16tof(h0)), s1 = bf16rne(v1 - bf16tof(h1));
        const size_t idx = ((size_t)(n * NT + (l >> 5)) * Mm + m) * TL + (l & 31);
        *(u32*)&awh[idx] = (u32)h0 | ((u32)h1 << 16);
        *(u32*)&awl[idx] = (u32)s0 | ((u32)s1 << 16);
    }
}

// ---------------------------------------------------------------------------
// Kernel B: MFMA main.  Block = (n, b), grid 1024 (n = bx>>5 so co-resident
// blocks share n -> alpha' L2-hot).  256 thr, wave w owns m-tile w.
// 40 KB LDS double-buffered -> 4 blocks/CU, 16 waves/CU.
// ---------------------------------------------------------------------------
__global__ __launch_bounds__(256, 4)
void wagg_mfma(const float* __restrict__ x_aug,
               const u16* __restrict__ awh, const u16* __restrict__ awl,
               float* __restrict__ out)
{
    const int n   = blockIdx.x >> 5;
    const int b   = blockIdx.x & 31;
    const int tid = threadIdx.x;

    __shared__ u16 ah_s[2][Mm * TLP];        // alpha-hi [m][l]  5 KB/stage
    __shared__ u16 al_s[2][Mm * TLP];        // alpha-lo
    __shared__ u16 xh_s[2][Ff * TLP];        // x-hi     [f][l]  5 KB/stage
    __shared__ u16 xl_s[2][Ff * TLP];        // x-lo             total 40 KB

    // staging ids
    const int fq = tid & 15;                 // f quad (f = 4*fq + j)
    const int lp = tid >> 4;                 // 0..15, l = 2*lp, 2*lp+1
    const int am = tid & 63;                 // alpha row m
    const int aq = tid >> 6;                 // alpha 16B chunk 0..3

    const float* xb = x_aug + (size_t)(b * Nn + n) * (Ll * Ff);
    const u16* ahg = awh + (size_t)n * NT * Mm * TL;
    const u16* alg = awl + (size_t)n * NT * Mm * TL;

    // compute ids
    const int lane = tid & 63;
    const int w    = tid >> 6;               // m-tile (m base = w*16)
    const int q    = lane >> 4;              // k-chunk / D-row-quad
    const int c    = lane & 15;              // A-row m / D-col f

    f32x4 acc[4];
    #pragma unroll
    for (int ft = 0; ft < 4; ++ft) acc[ft] = (f32x4){0.f, 0.f, 0.f, 0.f};

    float X[2][4];                           // [l row][j]
    uint4 AH, AL;

    // ---- prologue: load + convert + write tile 0 into buf 0 ----
    {
        const float* p = xb + (size_t)(2 * lp) * Ff + fq * 4;
        *(float4*)X[0] = *(const float4*)p;
        *(float4*)X[1] = *(const float4*)(p + Ff);
        AH = *(const uint4*)(ahg + (size_t)am * TL + aq * 8);
        AL = *(const uint4*)(alg + (size_t)am * TL + aq * 8);

        #pragma unroll
        for (int j = 0; j < 4; ++j) {
            const float v0 = X[0][j], v1 = X[1][j];
            const u16 h0 = bf16rne(v0), h1 = bf16rne(v1);
            const u16 s0 = bf16rne(v0 - bf16tof(h0)), s1 = bf16rne(v1 - bf16tof(h1));
            const u32 off = (u32)(fq * 4 + j) * TLP + 2 * lp;
            *(u32*)&xh_s[0][off] = (u32)h0 | ((u32)h1 << 16);
            *(u32*)&xl_s[0][off] = (u32)s0 | ((u32)s1 << 16);
        }
        *(uint4*)&ah_s[0][am * TLP + aq * 8] = AH;
        *(uint4*)&al_s[0][am * TLP + aq * 8] = AL;
    }
    __syncthreads();

    for (int tile = 0; tile < NT; ++tile) {
        const int cur = tile & 1, nxt = cur ^ 1;

        // prefetch tile+1 (global -> regs); consumed after MFMA section
        if (tile + 1 < NT) {
            const float* p = xb + (size_t)((tile + 1) * TL + 2 * lp) * Ff + fq * 4;
            *(float4*)X[0] = *(const float4*)p;
            *(float4*)X[1] = *(const float4*)(p + Ff);
            const size_t ao = (size_t)(tile + 1) * Mm * TL + am * TL + aq * 8;
            AH = *(const uint4*)(ahg + ao);
            AL = *(const uint4*)(alg + ao);
        }

        // fragment reads + 12 MFMA on current buffer
        short8 ahf, alf, xhf[4], xlf[4];
        {
            const u32 off = (u32)(w * 16 + c) * TLP + q * 8;
            ahf = *(const short8*)&ah_s[cur][off];
            alf = *(const short8*)&al_s[cur][off];
        }
        #pragma unroll
        for (int ft = 0; ft < 4; ++ft) {
            const u32 off = (u32)(ft * 16 + c) * TLP + q * 8;
            xhf[ft] = *(const short8*)&xh_s[cur][off];
            xlf[ft] = *(const short8*)&xl_s[cur][off];
        }
        #pragma unroll
        for (int ft = 0; ft < 4; ++ft) {
            acc[ft] = __builtin_amdgcn_mfma_f32_16x16x32_bf16(ahf, xhf[ft], acc[ft], 0, 0, 0);
            acc[ft] = __builtin_amdgcn_mfma_f32_16x16x32_bf16(ahf, xlf[ft], acc[ft], 0, 0, 0);
            acc[ft] = __builtin_amdgcn_mfma_f32_16x16x32_bf16(alf, xhf[ft], acc[ft], 0, 0, 0);
        }

        // convert + write staged tile+1 into the other buffer
        if (tile + 1 < NT) {
            #pragma unroll
            for (int j = 0; j < 4; ++j) {
                const float v0 = X[0][j], v1 = X[1][j];
                const u16 h0 = bf16rne(v0), h1 = bf16rne(v1);
                const u16 s0 = bf16rne(v0 - bf16tof(h0)), s1 = bf16rne(v1 - bf16tof(h1));
                const u32 off = (u32)(fq * 4 + j) * TLP + 2 * lp;
                *(u32*)&xh_s[nxt][off] = (u32)h0 | ((u32)h1 << 16);
                *(u32*)&xl_s[nxt][off] = (u32)s0 | ((u32)s1 << 16);
            }
            *(uint4*)&ah_s[nxt][am * TLP + aq * 8] = AH;
            *(uint4*)&al_s[nxt][am * TLP + aq * 8] = AL;
        }
        __syncthreads();
    }

    // ---- epilogue: D[row=q*4+r][col=c] -> out[b][n][m][f] ----
    float* ob = out + (size_t)(b * Nn + n) * (Mm * Ff);
    const int mbase = w * 16 + q * 4;
    #pragma unroll
    for (int r = 0; r < 4; ++r)
        #pragma unroll
        for (int ft = 0; ft < 4; ++ft)
            ob[(size_t)(mbase + r) * Ff + ft * 16 + c] = acc[ft][r];
}

// ---------------------------------------------------------------------------
// Fallback (ws too small): Round-1 monolithic kernel, known-correct.
// ---------------------------------------------------------------------------
__global__ __launch_bounds__(256, 1)
void wagg_fallback(const float* __restrict__ x_aug,
                   const float* __restrict__ t_in,
                   const float* __restrict__ t_left,
                   const float* __restrict__ t_right,
                   const float* __restrict__ kappa,
                   float* __restrict__ out)
{
    constexpr int BG = 4;
    const int n   = blockIdx.x >> 3;
    const int b0  = (blockIdx.x & 7) * BG;
    const int tid = threadIdx.x;

    __shared__ float xs[BG][TL][Ff];
    __shared__ float as_[TL][Mm];
    __shared__ float ts[Ll];
    __shared__ float dred[4][Mm];

    for (int i = tid; i < Ll; i += 256) ts[i] = t_in[i];

    const int am  = tid & 63;
    const int alq = tid >> 6;
    const float kap = kappa[n];
    const float kk  = fmaxf(kap, 0.0f) + log1pf(expf(-fabsf(kap)));
    const float ik  = 1.0f / kk;
    const float tlv = t_left [n * Mm + am];
    const float trv = t_right[n * Mm + am];

    const int bs   = tid >> 6;
    const int lane = tid & 63;
    const int mi   = (lane >> 3) << 3;
    const int fi   = (lane & 7) << 3;

    float acc[8][8];
    #pragma unroll
    for (int i = 0; i < 8; ++i)
        #pragma unroll
        for (int j = 0; j < 8; ++j) acc[i][j] = 0.0f;

    float4 stg[8];
    float  aval[8];
    float  dpart = 0.0f;

    __syncthreads();
    {
        #pragma unroll
        for (int k = 0; k < 8; ++k) {
            const int g = k * 256 + tid;
            const int gbs = g >> 9, r = (g >> 4) & 31, fqq = (g & 15) << 2;
            stg[k] = *(const float4*)(x_aug
                + (size_t)((b0 + gbs) * Nn + n) * (Ll * Ff) + (size_t)r * Ff + fqq);
        }
        #pragma unroll
        for (int i = 0; i < 8; ++i) {
            const float tv = ts[alq + (i << 2)];
            const float a = 1.0f / ((1.0f + __expf((tv - trv) * ik)) *
                                    (1.0f + __expf((tlv - tv) * ik)));
            aval[i] = a; dpart += a;
        }
        #pragma unroll
        for (int k = 0; k < 8; ++k) ((float4*)xs)[k * 256 + tid] = stg[k];
        #pragma unroll
        for (int i = 0; i < 8; ++i) as_[alq + (i << 2)][am] = aval[i];
    }
    __syncthreads();

    for (int tile = 0; tile < NT; ++tile) {
        if (tile + 1 < NT) {
            const int l0 = (tile + 1) * TL;
            #pragma unroll
            for (int k = 0; k < 8; ++k) {
                const int g = k * 256 + tid;
                const int gbs = g >> 9, r = (g >> 4) & 31, fqq = (g & 15) << 2;
                stg[k] = *(const float4*)(x_aug
                    + (size_t)((b0 + gbs) * Nn + n) * (Ll * Ff)
                    + (size_t)(l0 + r) * Ff + fqq);
            }
            #pragma unroll
            for (int i = 0; i < 8; ++i) {
                const float tv = ts[l0 + alq + (i << 2)];
                const float a = 1.0f / ((1.0f + __expf((tv - trv) * ik)) *
                                        (1.0f + __expf((tlv - tv) * ik)));
                aval[i] = a; dpart += a;
            }
        }
        #pragma unroll 4
        for (int lt = 0; lt < TL; ++lt) {
            float av[8], xv[8];
            *(float4*)&av[0] = *(const float4*)&as_[lt][mi];
            *(float4*)&av[4] = *(const float4*)&as_[lt][mi + 4];
            *(float4*)&xv[0] = *(const float4*)&xs[bs][lt][fi];
            *(float4*)&xv[4] = *(const float4*)&xs[bs][lt][fi + 4];
            #pragma unroll
            for (int i = 0; i < 8; ++i)
                #pragma unroll
                for (int j = 0; j < 8; ++j)
                    acc[i][j] = fmaf(av[i], xv[j], acc[i][j]);
        }
        __syncthreads();
        if (tile + 1 < NT) {
            #pragma unroll
            for (int k = 0; k < 8; ++k) ((float4*)xs)[k * 256 + tid] = stg[k];
            #pragma unroll
            for (int i = 0; i < 8; ++i) as_[alq + (i << 2)][am] = aval[i];
        }
        __syncthreads();
    }

    dred[alq][am] = dpart;
    __syncthreads();
    if (tid < Mm) {
        const float d = dred[0][tid] + dred[1][tid] + dred[2][tid] + dred[3][tid];
        dred[0][tid] = 1.0f / (d + EPSV);
    }
    __syncthreads();

    const size_t obase = ((size_t)(b0 + bs) * Nn + n) * Mm;
    #pragma unroll
    for (int i = 0; i < 8; ++i) {
        const float inv = dred[0][mi + i];
        float o[8];
        #pragma unroll
        for (int j = 0; j < 8; ++j) o[j] = acc[i][j] * inv;
        float* dst = out + (obase + (mi + i)) * Ff + fi;
        *(float4*)dst       = *(float4*)&o[0];
        *((float4*)dst + 1) = *(float4*)&o[4];
    }
}

extern "C" void kernel_launch(void* const* d_in, const int* in_sizes, int n_in,
                              void* d_out, int out_size, void* d_ws, size_t ws_size,
                              hipStream_t stream)
{
    const float* x_aug   = (const float*)d_in[0];
    const float* t_in    = (const float*)d_in[1];
    const float* t_left  = (const float*)d_in[2];
    const float* t_right = (const float*)d_in[3];
    const float* kappa   = (const float*)d_in[4];
    float* out = (float*)d_out;

    if (ws_size >= WS_BYTES) {
        float* denom = (float*)d_ws;
        u16* awh = (u16*)(denom + DEN_ELEMS);
        u16* awl = awh + AW_ELEMS;
        hipLaunchKernelGGL(denom_kernel, dim3(Nn * 8), dim3(256), 0, stream,
                           t_in, t_left, t_right, kappa, denom);
        hipLaunchKernelGGL(alpha_kernel, dim3(Nn * 8), dim3(256), 0, stream,
                           t_in, t_left, t_right, kappa, denom, awh, awl);
        hipLaunchKernelGGL(wagg_mfma, dim3(Nn * Bb), dim3(256), 0, stream,
                           x_aug, awh, awl, out);
    } else {
        hipLaunchKernelGGL(wagg_fallback, dim3(Nn * 8), dim3(256), 0, stream,
                           x_aug, t_in, t_left, t_right, kappa, out);
    }
}

// Round 5
// 206.312 us; speedup vs baseline: 1.6963x; 1.0589x over previous
//
#include <hip/hip_runtime.h>
#include <math.h>

typedef unsigned short u16;
typedef unsigned int   u32;
typedef __attribute__((ext_vector_type(8))) short short8;
typedef __attribute__((ext_vector_type(4))) float f32x4;

namespace {
constexpr int Bb = 32, Nn = 32, Ll = 512, Mm = 64, Ff = 64;
constexpr int TL  = 32;           // K-tile in l (= one MFMA K step)
constexpr int NT  = Ll / TL;      // 16
constexpr int TLP = 40;           // padded row (u16): 80B stride, conflict-free b128 frags
constexpr float EPSV = 1e-8f;
}

__device__ __forceinline__ u16 bf16rne(float x) {
    u32 u = __float_as_uint(x);
    return (u16)((u + 0x7fffu + ((u >> 16) & 1u)) >> 16);
}
__device__ __forceinline__ float bf16tof(u16 h) {
    return __uint_as_float(((u32)h) << 16);
}

// ---------------------------------------------------------------------------
// Fused kernel: block = (b,n), grid 1024, 256 thr, 40 KB LDS dbuf ->
// 4 blocks/CU.  Each block computes its own alpha per tile (1 exp + 1 rcp
// per element via u = e^{t/k}, A = e^{-tr/k}, B = e^{tl/k}:
// alpha = u / ((1+A*u)*(u+B)) ).  Denominator reduced post-loop in LDS
// (aliased onto freed stage buffer), applied in epilogue.
// ---------------------------------------------------------------------------
__global__ __launch_bounds__(256, 4)
void wagg_fused(const float* __restrict__ x_aug,
                const float* __restrict__ t_in,
                const float* __restrict__ t_left,
                const float* __restrict__ t_right,
                const float* __restrict__ kappa,
                float* __restrict__ out)
{
    const int n   = blockIdx.x & 31;
    const int b   = blockIdx.x >> 5;
    const int tid = threadIdx.x;

    __shared__ u16 ah_s[2][Mm * TLP];        // alpha-hi [m][l]  5 KB/stage
    __shared__ u16 al_s[2][Mm * TLP];        // alpha-lo
    __shared__ u16 xh_s[2][Ff * TLP];        // x-hi     [f][l]
    __shared__ u16 xl_s[2][Ff * TLP];        // x-lo             total 40 KB

    // ---- x staging ids: lane strip over f, row pair over l ----
    const int fq  = tid & 15;                // f quad (f = 4*fq + j)
    const int lp2 = tid >> 4;                // 0..15 -> l = 2*lp2, 2*lp2+1

    // ---- alpha ids: wave wv covers m in [wv*16, wv*16+16) ----
    const int wv   = tid >> 6;
    const int lane = tid & 63;
    const int ma   = wv * 16 + (lane >> 2);  // this thread's m
    const int lqa  = lane & 3;               // l chunk: l = lqa*8 + 0..7

    // ---- MFMA ids: wave = (m-half, f-half), 2x2 16x16 tiles ----
    const int mh = wv & 1;                   // m base = mh*32
    const int fh = wv >> 1;                  // f base = fh*32
    const int q  = lane >> 4;                // k-chunk / D-row-quad
    const int c  = lane & 15;                // A/B row select / D-col

    const float* xb = x_aug + (size_t)(b * Nn + n) * (Ll * Ff);

    // ---- prologue scalars ----
    const float kap = kappa[n];
    const float kk  = fmaxf(kap, 0.0f) + log1pf(expf(-fabsf(kap))); // softplus
    const float ik  = 1.0f / kk;
    const float tlv = t_left [n * Mm + ma];
    const float trv = t_right[n * Mm + ma];
    const float Ac  = __expf(-trv * ik);     // e^{-tr/k}
    const float Bc  = __expf( tlv * ik);     // e^{+tl/k}

    f32x4 acc[2][2];
    #pragma unroll
    for (int mi = 0; mi < 2; ++mi)
        #pragma unroll
        for (int fi = 0; fi < 2; ++fi)
            acc[mi][fi] = (f32x4){0.f, 0.f, 0.f, 0.f};

    float X0[4], X1[4];                      // staged x rows (l, l+1)
    float T[8];                              // staged t values
    float dsum = 0.0f;                       // fp32 denominator partial

    // stage (convert x + compute alpha) into buffer `buf`
    auto stage = [&](int buf) {
        // x: f32 -> bf16 hi/lo, transpose to [f][l]
        #pragma unroll
        for (int j = 0; j < 4; ++j) {
            const float v0 = X0[j], v1 = X1[j];
            const u16 h0 = bf16rne(v0), h1 = bf16rne(v1);
            const u16 s0 = bf16rne(v0 - bf16tof(h0)), s1 = bf16rne(v1 - bf16tof(h1));
            const u32 off = (u32)(fq * 4 + j) * TLP + 2 * lp2;
            *(u32*)&xh_s[buf][off] = (u32)h0 | ((u32)h1 << 16);
            *(u32*)&xl_s[buf][off] = (u32)s0 | ((u32)s1 << 16);
        }
        // alpha: 8 values for (ma, l = lqa*8 + jj)
        u32 hi[4], lo[4];
        #pragma unroll
        for (int jj = 0; jj < 8; jj += 2) {
            const float u0 = __expf(T[jj]     * ik);
            const float u1 = __expf(T[jj + 1] * ik);
            const float d0 = fmaf(Ac, u0, 1.0f) * (u0 + Bc);
            const float d1 = fmaf(Ac, u1, 1.0f) * (u1 + Bc);
            const float a0 = u0 * __builtin_amdgcn_rcpf(d0);
            const float a1 = u1 * __builtin_amdgcn_rcpf(d1);
            dsum += a0 + a1;
            const u16 h0 = bf16rne(a0), h1 = bf16rne(a1);
            const u16 s0 = bf16rne(a0 - bf16tof(h0)), s1 = bf16rne(a1 - bf16tof(h1));
            hi[jj >> 1] = (u32)h0 | ((u32)h1 << 16);
            lo[jj >> 1] = (u32)s0 | ((u32)s1 << 16);
        }
        const u32 aoff = (u32)ma * TLP + lqa * 8;
        *(uint4*)&ah_s[buf][aoff] = make_uint4(hi[0], hi[1], hi[2], hi[3]);
        *(uint4*)&al_s[buf][aoff] = make_uint4(lo[0], lo[1], lo[2], lo[3]);
    };

    // ---- prologue: tile 0 ----
    {
        const float* p = xb + (size_t)(2 * lp2) * Ff + fq * 4;
        *(float4*)X0 = *(const float4*)p;
        *(float4*)X1 = *(const float4*)(p + Ff);
        *(float4*)&T[0] = *(const float4*)&t_in[lqa * 8];
        *(float4*)&T[4] = *(const float4*)&t_in[lqa * 8 + 4];
        stage(0);
    }
    __syncthreads();

    for (int tile = 0; tile < NT; ++tile) {
        const int cur = tile & 1, nxt = cur ^ 1;

        // prefetch tile+1 (global -> regs); consumed after MFMA section
        if (tile + 1 < NT) {
            const int l0 = (tile + 1) * TL;
            const float* p = xb + (size_t)(l0 + 2 * lp2) * Ff + fq * 4;
            *(float4*)X0 = *(const float4*)p;
            *(float4*)X1 = *(const float4*)(p + Ff);
            *(float4*)&T[0] = *(const float4*)&t_in[l0 + lqa * 8];
            *(float4*)&T[4] = *(const float4*)&t_in[l0 + lqa * 8 + 4];
        }

        // fragment reads (8 x b128) + 12 MFMA on current buffer
        short8 ahf[2], alf[2], xhf[2], xlf[2];
        #pragma unroll
        for (int mi = 0; mi < 2; ++mi) {
            const u32 off = (u32)(mh * 32 + mi * 16 + c) * TLP + q * 8;
            ahf[mi] = *(const short8*)&ah_s[cur][off];
            alf[mi] = *(const short8*)&al_s[cur][off];
        }
        #pragma unroll
        for (int fi = 0; fi < 2; ++fi) {
            const u32 off = (u32)(fh * 32 + fi * 16 + c) * TLP + q * 8;
            xhf[fi] = *(const short8*)&xh_s[cur][off];
            xlf[fi] = *(const short8*)&xl_s[cur][off];
        }
        #pragma unroll
        for (int mi = 0; mi < 2; ++mi)
            #pragma unroll
            for (int fi = 0; fi < 2; ++fi) {
                acc[mi][fi] = __builtin_amdgcn_mfma_f32_16x16x32_bf16(
                    ahf[mi], xhf[fi], acc[mi][fi], 0, 0, 0);
                acc[mi][fi] = __builtin_amdgcn_mfma_f32_16x16x32_bf16(
                    ahf[mi], xlf[fi], acc[mi][fi], 0, 0, 0);
                acc[mi][fi] = __builtin_amdgcn_mfma_f32_16x16x32_bf16(
                    alf[mi], xhf[fi], acc[mi][fi], 0, 0, 0);
            }

        if (tile + 1 < NT) stage(nxt);
        __syncthreads();
    }

    // ---- denominator reduce (alias freed stage buf 0) ----
    float* dred = (float*)&xh_s[0][0];       // 256 f32 partials
    float* invp = dred + 256;                // 64 f32 inverses (within 5 KB)
    dred[lqa * 64 + ma] = dsum;
    __syncthreads();
    if (tid < Mm) {
        const float d = dred[tid] + dred[64 + tid] + dred[128 + tid] + dred[192 + tid];
        invp[tid] = __builtin_amdgcn_rcpf(d + EPSV);
    }
    __syncthreads();

    // ---- epilogue: scale by 1/(denom+eps), store ----
    float* ob = out + (size_t)(b * Nn + n) * (Mm * Ff);
    #pragma unroll
    for (int mi = 0; mi < 2; ++mi) {
        const int mbase = mh * 32 + mi * 16 + q * 4;
        float iv[4];
        #pragma unroll
        for (int r = 0; r < 4; ++r) iv[r] = invp[mbase + r];
        #pragma unroll
        for (int fi = 0; fi < 2; ++fi) {
            const int f = fh * 32 + fi * 16 + c;
            #pragma unroll
            for (int r = 0; r < 4; ++r)
                ob[(size_t)(mbase + r) * Ff + f] = acc[mi][fi][r] * iv[r];
        }
    }
}

extern "C" void kernel_launch(void* const* d_in, const int* in_sizes, int n_in,
                              void* d_out, int out_size, void* d_ws, size_t ws_size,
                              hipStream_t stream)
{
    const float* x_aug   = (const float*)d_in[0];
    const float* t_in    = (const float*)d_in[1];
    const float* t_left  = (const float*)d_in[2];
    const float* t_right = (const float*)d_in[3];
    const float* kappa   = (const float*)d_in[4];
    float* out = (float*)d_out;

    hipLaunchKernelGGL(wagg_fused, dim3(Bb * Nn), dim3(256), 0, stream,
                       x_aug, t_in, t_left, t_right, kappa, out);
}